// Round 5
// baseline (258.717 us; speedup 1.0000x reference)
//
#include <hip/hip_runtime.h>
#include <hip/hip_fp16.h>
#include <stdint.h>

#define NT 256
#define RPB 32             // rows per tile
#define XSTR 80            // bytes per k-slot: 40 halfs (32 rows + 8 pad), 16B-aligned

// ws layout (byte offsets). Tables repacked per-thread-contiguous: slot = (t&63)*8 + (t>>6)
#define WS_P3   0          // 512 x 8B  {o0|o1<<16, o2|c3h<<16}   -> thread ts owns [ts*64 .. ts*64+63]
#define WS_P4   4096       // 512 x 16B {o0|o1, o2|o3, c4h, 0}    -> thread ts owns 128B
#define WS_P5   12288      // 512 x 16B {o0|o1, o2|o3, o4|c5h, 0} -> thread ts owns 128B
#define WS_BUTH 20480      // 64x64 halfs row-major by j: buTh[j*64+i] = (i<j) ? half(b[i][j]) : 0

static __device__ __forceinline__ __half2 H2(unsigned u) {
    return __builtin_bit_cast(__half2, u);
}
static __device__ __forceinline__ unsigned short f2hbits(float f) {
    __half h = __float2half(f);
    return __builtin_bit_cast(unsigned short, h);
}

__global__ void prepack(const float* __restrict__ b,
                        const int* __restrict__ i3, const float* __restrict__ c3,
                        const int* __restrict__ i4, const float* __restrict__ c4,
                        const int* __restrict__ i5, const float* __restrict__ c5,
                        unsigned char* __restrict__ ws)
{
    const int g = blockIdx.x * NT + threadIdx.x;   // 16 x 256 = 4096
    if (g < 4096) {
        int j = g >> 6, i = g & 63;
        float v = (i < j) ? b[i * 64 + j] : 0.0f;  // transposed strict-upper
        ((unsigned short*)(ws + WS_BUTH))[g] = f2hbits(v);
    }
    if (g < 512) {
        const int slot = (g & 63) * 8 + (g >> 6);  // [ts][m] layout
        unsigned o0, o1, o2, o3, o4;
        o0 = (unsigned)i3[3*g+0] * XSTR; o1 = (unsigned)i3[3*g+1] * XSTR; o2 = (unsigned)i3[3*g+2] * XSTR;
        ((uint2*)(ws + WS_P3))[slot] = make_uint2(o0 | (o1 << 16), o2 | ((unsigned)f2hbits(c3[g]) << 16));
        o0 = (unsigned)i4[4*g+0] * XSTR; o1 = (unsigned)i4[4*g+1] * XSTR;
        o2 = (unsigned)i4[4*g+2] * XSTR; o3 = (unsigned)i4[4*g+3] * XSTR;
        ((uint4*)(ws + WS_P4))[slot] = make_uint4(o0 | (o1 << 16), o2 | (o3 << 16), (unsigned)f2hbits(c4[g]), 0u);
        o0 = (unsigned)i5[5*g+0] * XSTR; o1 = (unsigned)i5[5*g+1] * XSTR;
        o2 = (unsigned)i5[5*g+2] * XSTR; o3 = (unsigned)i5[5*g+3] * XSTR;
        o4 = (unsigned)i5[5*g+4] * XSTR;
        ((uint4*)(ws + WS_P5))[slot] = make_uint4(o0 | (o1 << 16), o2 | (o3 << 16), o4 | ((unsigned)f2hbits(c5[g]) << 16), 0u);
    }
}

static __device__ __forceinline__ void qfma(__half2 bb, uint4 xk, __half2 d[4]) {
    d[0] = __hfma2(bb, H2(xk.x), d[0]);
    d[1] = __hfma2(bb, H2(xk.y), d[1]);
    d[2] = __hfma2(bb, H2(xk.z), d[2]);
    d[3] = __hfma2(bb, H2(xk.w), d[3]);
}
static __device__ __forceinline__ void pmul(const uint4& a, __half2 p[4]) {
    p[0] = __hmul2(p[0], H2(a.x));
    p[1] = __hmul2(p[1], H2(a.y));
    p[2] = __hmul2(p[2], H2(a.z));
    p[3] = __hmul2(p[3], H2(a.w));
}
static __device__ __forceinline__ void pacc(__half2 c2, const __half2 p[4], __half2 acc[4]) {
    acc[0] = __hfma2(c2, p[0], acc[0]);
    acc[1] = __hfma2(c2, p[1], acc[1]);
    acc[2] = __hfma2(c2, p[2], acc[2]);
    acc[3] = __hfma2(c2, p[3], acc[3]);
}

// R0 structure, templated over TILES (tiles processed sequentially per block).
// TILES=1, grid 1024: the production config (exact R0 revert).
// TILES=2, grid 512: PROBE dispatch — same total work at half parallelism, so its
// duration ~2x one poly pass. If poly is ~45us (cold-gather model) the probe lands
// >77us and surfaces in rocprof top-5 WITH counters; if poly is ~8-10us (L3-warm
// model: the harness input-restore copy leaves x L3-resident) it stays hidden and
// total only rises ~20us. Idempotent: rewrites out with identical values.
template<int TILES>
__global__ __launch_bounds__(NT, 4)
void poly_kern(const float* __restrict__ x, const int* __restrict__ S,
               const float* __restrict__ a,
               const unsigned char* __restrict__ ws, float* __restrict__ out)
{
    __shared__ __align__(16) __half xS[64 * 40];   // [k][32 rows (fp16) + 8 pad]
    __shared__ float red[4][4][8];                 // [wave][rg][row-in-group]

    const int tid  = threadIdx.x;

    const int rg = tid & 3;
    const int ts = tid >> 2;

    // ---- batched register preload of this thread's table entries (once per block) ----
    uint2 e3[8];
    uint4 e4[8], e5[8], bw[8];
    {
        const uint4* s3 = (const uint4*)(ws + WS_P3 + ts * 64);
        #pragma unroll
        for (int i = 0; i < 4; ++i) ((uint4*)e3)[i] = s3[i];
        const uint4* s4 = (const uint4*)(ws + WS_P4 + ts * 128);
        #pragma unroll
        for (int i = 0; i < 8; ++i) e4[i] = s4[i];
        const uint4* s5 = (const uint4*)(ws + WS_P5 + ts * 128);
        #pragma unroll
        for (int i = 0; i < 8; ++i) e5[i] = s5[i];
        const uint4* sb = (const uint4*)(ws + WS_BUTH + ts * 128);
        #pragma unroll
        for (int i = 0; i < 8; ++i) bw[i] = sb[i];
    }
    const float av = a[ts];
    const int k = tid & 63, q = tid >> 6;
    const int sk = S[k];

    for (int t = 0; t < TILES; ++t) {
        const int row0 = (blockIdx.x * TILES + t) * RPB;

        // ---- gather + fp16 pack: lane k, wave q loads rows q*8..q*8+7 ----
        {
            const float* xc = x + (size_t)row0 * 1024 + sk;
            float v[8];
            #pragma unroll
            for (int m = 0; m < 8; ++m) v[m] = xc[(size_t)(q * 8 + m) * 1024];
            uint4 pk;
            pk.x = __builtin_bit_cast(unsigned, __floats2half2_rn(v[0], v[1]));
            pk.y = __builtin_bit_cast(unsigned, __floats2half2_rn(v[2], v[3]));
            pk.z = __builtin_bit_cast(unsigned, __floats2half2_rn(v[4], v[5]));
            pk.w = __builtin_bit_cast(unsigned, __floats2half2_rn(v[6], v[7]));
            *(uint4*)((char*)xS + k * XSTR + q * 16) = pk;
        }
        __syncthreads();

        // ---- compute: rg owns rows rg*8..rg*8+7 (4 half2), ts = j / term slice (0..63) ----
        const char* xb = (const char*)xS + rg * 16;

        // quad (triangular): d = sum_{i<ts} buT[ts][i] * x_i ; preloaded bw, masked unroll
        __half2 d[4] = {H2(0u), H2(0u), H2(0u), H2(0u)};
        {
            const int nii = (ts + 7) >> 3;             // 0..8; varies <=1 within a wave
            #pragma unroll
            for (int g = 0; g < 8; ++g) {
                if (g < nii) {
                    uint4 w4 = bw[g];
                    const char* xkb = xb + g * 8 * XSTR;
                    unsigned pw[4] = {w4.x, w4.y, w4.z, w4.w};
                    #pragma unroll
                    for (int p = 0; p < 4; ++p) {
                        __half2 blo = __half2half2(__ushort_as_half((unsigned short)(pw[p] & 0xFFFFu)));
                        __half2 bhi = __half2half2(__ushort_as_half((unsigned short)(pw[p] >> 16)));
                        uint4 x0 = *(const uint4*)(xkb + (2 * p + 0) * XSTR);
                        uint4 x1 = *(const uint4*)(xkb + (2 * p + 1) * XSTR);
                        qfma(blo, x0, d);
                        qfma(bhi, x1, d);
                    }
                }
            }
        }
        __half2 acc[4];
        {
            __half2 a2 = __half2half2(__float2half(av));
            uint4 xj = *(const uint4*)(xb + ts * XSTR);
            acc[0] = __hmul2(__hadd2(a2, d[0]), H2(xj.x));
            acc[1] = __hmul2(__hadd2(a2, d[1]), H2(xj.y));
            acc[2] = __hmul2(__hadd2(a2, d[2]), H2(xj.z));
            acc[3] = __hmul2(__hadd2(a2, d[3]), H2(xj.w));
        }

        // ---- monomials: entries preloaded in registers, loops are pure LDS+VALU ----
        #pragma unroll
        for (int m = 0; m < 8; ++m) {
            uint2 p = e3[m];
            uint4 v0 = *(const uint4*)(xb + (p.x & 0xFFFFu));
            uint4 v1 = *(const uint4*)(xb + (p.x >> 16));
            uint4 v2 = *(const uint4*)(xb + (p.y & 0xFFFFu));
            __half2 pr[4] = {H2(v0.x), H2(v0.y), H2(v0.z), H2(v0.w)};
            pmul(v1, pr);
            pmul(v2, pr);
            pacc(__half2half2(__ushort_as_half((unsigned short)(p.y >> 16))), pr, acc);
        }
        #pragma unroll
        for (int m = 0; m < 8; ++m) {
            uint4 p = e4[m];
            uint4 v0 = *(const uint4*)(xb + (p.x & 0xFFFFu));
            uint4 v1 = *(const uint4*)(xb + (p.x >> 16));
            uint4 v2 = *(const uint4*)(xb + (p.y & 0xFFFFu));
            uint4 v3 = *(const uint4*)(xb + (p.y >> 16));
            __half2 pr[4] = {H2(v0.x), H2(v0.y), H2(v0.z), H2(v0.w)};
            pmul(v1, pr);
            pmul(v2, pr);
            pmul(v3, pr);
            pacc(__half2half2(__ushort_as_half((unsigned short)(p.z & 0xFFFFu))), pr, acc);
        }
        #pragma unroll
        for (int m = 0; m < 8; ++m) {
            uint4 p = e5[m];
            uint4 v0 = *(const uint4*)(xb + (p.x & 0xFFFFu));
            uint4 v1 = *(const uint4*)(xb + (p.x >> 16));
            uint4 v2 = *(const uint4*)(xb + (p.y & 0xFFFFu));
            uint4 v3 = *(const uint4*)(xb + (p.y >> 16));
            uint4 v4 = *(const uint4*)(xb + (p.z & 0xFFFFu));
            __half2 pr[4] = {H2(v0.x), H2(v0.y), H2(v0.z), H2(v0.w)};
            pmul(v1, pr);
            pmul(v2, pr);
            pmul(v3, pr);
            pmul(v4, pr);
            pacc(__half2half2(__ushort_as_half((unsigned short)(p.z >> 16))), pr, acc);
        }

        // ---- reduce 16 ts-partials per wave in fp32, then cross-wave via LDS ----
        float f[8];
        #pragma unroll
        for (int e = 0; e < 4; ++e) {
            f[2 * e]     = __low2float(acc[e]);
            f[2 * e + 1] = __high2float(acc[e]);
        }
        #pragma unroll
        for (int mask = 4; mask <= 32; mask <<= 1) {
            #pragma unroll
            for (int r = 0; r < 8; ++r) f[r] += __shfl_xor(f[r], mask, 64);
        }
        const int w = tid >> 6, lane = tid & 63;
        if (lane < 4) {
            #pragma unroll
            for (int r = 0; r < 8; ++r) red[w][lane][r] = f[r];
        }
        __syncthreads();
        if (tid < 32) {
            int g = tid >> 3, e = tid & 7;
            out[row0 + tid] = red[0][g][e] + red[1][g][e] + red[2][g][e] + red[3][g][e];
        }
        // next tile's xS writes race nothing: red-readers pass the tile-entry
        // __syncthreads before red is rewritten (post-compute), xS != red.
    }
}

extern "C" void kernel_launch(void* const* d_in, const int* in_sizes, int n_in,
                              void* d_out, int out_size, void* d_ws, size_t ws_size,
                              hipStream_t stream) {
    const float* x  = (const float*)d_in[0];
    const int*   S  = (const int*)d_in[1];
    const float* a  = (const float*)d_in[2];
    const float* b  = (const float*)d_in[3];
    const int*   i3 = (const int*)d_in[4];
    const float* c3 = (const float*)d_in[5];
    const int*   i4 = (const int*)d_in[6];
    const float* c4 = (const float*)d_in[7];
    const int*   i5 = (const int*)d_in[8];
    const float* c5 = (const float*)d_in[9];
    unsigned char* ws = (unsigned char*)d_ws;
    float* out = (float*)d_out;

    prepack<<<16, NT, 0, stream>>>(b, i3, c3, i4, c4, i5, c5, ws);
    poly_kern<1><<<32768 / RPB, NT, 0, stream>>>(x, S, a, ws, out);
    // PROBE: same work at half parallelism -> ~2x single-pass duration; surfaces
    // poly counters in rocprof top-5 iff a single pass is >~40us (cold-gather model).
    poly_kern<2><<<32768 / (2 * RPB), NT, 0, stream>>>(x, S, a, ws, out);
}

// Round 6
// 203.640 us; speedup vs baseline: 1.2705x; 1.2705x over previous
//
#include <hip/hip_runtime.h>
#include <hip/hip_fp16.h>
#include <stdint.h>

#define NT 256
#define RPB 32             // rows per block
#define XSTR 80            // bytes per k-slot: 40 halfs (32 rows + 8 pad), 16B-aligned

// ws: one contiguous 28KB table block, copied verbatim into LDS per block.
// All e-layouts are [m][ts] (slot = g = m*64 + ts) so a wave's 16 consecutive ts
// read distinct/2-way banks (free). buT2 is group-major [g][ts] 16B chunks.
#define WS_P3   0          // 512 x 8B  {o0|o1<<16, o2|c3h<<16}
#define WS_P4   4096       // 512 x 16B {o0|o1, o2|o3, c4h, 0}
#define WS_P5   12288      // 512 x 16B {o0|o1, o2|o3, o4|c5h, 0}
#define WS_BUTH 20480      // 8 g x 64 ts x 16B: halfs buT[ts][8g..8g+7], buT[ts][i]=(i<ts)?b[i][ts]:0
#define WS_TBL  28672      // total staged bytes

static __device__ __forceinline__ __half2 H2(unsigned u) {
    return __builtin_bit_cast(__half2, u);
}
static __device__ __forceinline__ unsigned short f2hbits(float f) {
    __half h = __float2half(f);
    return __builtin_bit_cast(unsigned short, h);
}

__global__ void prepack(const float* __restrict__ b,
                        const int* __restrict__ i3, const float* __restrict__ c3,
                        const int* __restrict__ i4, const float* __restrict__ c4,
                        const int* __restrict__ i5, const float* __restrict__ c5,
                        unsigned char* __restrict__ ws)
{
    const int g = blockIdx.x * NT + threadIdx.x;   // 16 x 256 = 4096
    if (g < 4096) {
        // coalesced row-major read of b; scattered 2B write into group-major buT2
        const int i = g >> 6, j = g & 63;
        float v = (i < j) ? b[g] : 0.0f;           // strict upper, transposed on write
        ((unsigned short*)(ws + WS_BUTH))[(i >> 3) * 512 + j * 8 + (i & 7)] = f2hbits(v);
    }
    if (g < 512) {
        // identity slot = g -> LDS layout [m][ts] with m=g>>6, ts=g&63
        unsigned o0, o1, o2, o3, o4;
        o0 = (unsigned)i3[3*g+0] * XSTR; o1 = (unsigned)i3[3*g+1] * XSTR; o2 = (unsigned)i3[3*g+2] * XSTR;
        ((uint2*)(ws + WS_P3))[g] = make_uint2(o0 | (o1 << 16), o2 | ((unsigned)f2hbits(c3[g]) << 16));
        o0 = (unsigned)i4[4*g+0] * XSTR; o1 = (unsigned)i4[4*g+1] * XSTR;
        o2 = (unsigned)i4[4*g+2] * XSTR; o3 = (unsigned)i4[4*g+3] * XSTR;
        ((uint4*)(ws + WS_P4))[g] = make_uint4(o0 | (o1 << 16), o2 | (o3 << 16), (unsigned)f2hbits(c4[g]), 0u);
        o0 = (unsigned)i5[5*g+0] * XSTR; o1 = (unsigned)i5[5*g+1] * XSTR;
        o2 = (unsigned)i5[5*g+2] * XSTR; o3 = (unsigned)i5[5*g+3] * XSTR;
        o4 = (unsigned)i5[5*g+4] * XSTR;
        ((uint4*)(ws + WS_P5))[g] = make_uint4(o0 | (o1 << 16), o2 | (o3 << 16), o4 | ((unsigned)f2hbits(c5[g]) << 16), 0u);
    }
}

static __device__ __forceinline__ void qfma(__half2 bb, uint4 xk, __half2 d[4]) {
    d[0] = __hfma2(bb, H2(xk.x), d[0]);
    d[1] = __hfma2(bb, H2(xk.y), d[1]);
    d[2] = __hfma2(bb, H2(xk.z), d[2]);
    d[3] = __hfma2(bb, H2(xk.w), d[3]);
}
static __device__ __forceinline__ void pmul(const uint4& a, __half2 p[4]) {
    p[0] = __hmul2(p[0], H2(a.x));
    p[1] = __hmul2(p[1], H2(a.y));
    p[2] = __hmul2(p[2], H2(a.z));
    p[3] = __hmul2(p[3], H2(a.w));
}
static __device__ __forceinline__ void pacc(__half2 c2, const __half2 p[4], __half2 acc[4]) {
    acc[0] = __hfma2(c2, p[0], acc[0]);
    acc[1] = __hfma2(c2, p[1], acc[1]);
    acc[2] = __hfma2(c2, p[2], acc[2]);
    acc[3] = __hfma2(c2, p[3], acc[3]);
}

// SPILL FIX (R5 probe evidence: VGPR_Count=64 + WRITE_SIZE=71MB = table arrays in
// scratch, round-tripped through HBM). All tables now live in LDS, staged once per
// block with a coalesced 28KB copy; register peak ~70 -> zero scratch.
// LDS: 5120 (xS) + 28672 (tables) + 512 (red) = 34304 B -> 4 blocks/CU, 16 waves/CU.
__global__ __launch_bounds__(NT, 4)
void poly_main(const float* __restrict__ x, const int* __restrict__ S,
               const float* __restrict__ a,
               const unsigned char* __restrict__ ws, float* __restrict__ out)
{
    __shared__ __align__(16) __half xS[64 * 40];           // [k][32 rows (fp16) + 8 pad]
    __shared__ __align__(16) unsigned char tbl[WS_TBL];    // e3/e4/e5/buT2, ws image
    __shared__ float red[4][4][8];                         // [wave][rg][row-in-group]

    const int tid  = threadIdx.x;
    const int row0 = blockIdx.x * RPB;

    const int rg = tid & 3;
    const int ts = tid >> 2;

    // ---- x gather FIRST: longest-latency (HBM, scattered) loads issue early ----
    const int k = tid & 63, q = tid >> 6;
    const int sk = S[k];
    const float* xc = x + (size_t)row0 * 1024 + sk;
    float v[8];
    #pragma unroll
    for (int m = 0; m < 8; ++m) v[m] = xc[(size_t)(q * 8 + m) * 1024];

    // ---- stage all tables into LDS: 7 x uint4 per thread, fully coalesced ----
    {
        const uint4* src = (const uint4*)ws;
        uint4* dst = (uint4*)tbl;
        #pragma unroll
        for (int i = 0; i < 7; ++i) dst[i * NT + tid] = src[i * NT + tid];
    }
    const float av = a[ts];

    // ---- fp16 pack of gathered x: lane k, wave q wrote rows q*8..q*8+7 ----
    {
        uint4 pk;
        pk.x = __builtin_bit_cast(unsigned, __floats2half2_rn(v[0], v[1]));
        pk.y = __builtin_bit_cast(unsigned, __floats2half2_rn(v[2], v[3]));
        pk.z = __builtin_bit_cast(unsigned, __floats2half2_rn(v[4], v[5]));
        pk.w = __builtin_bit_cast(unsigned, __floats2half2_rn(v[6], v[7]));
        *(uint4*)((char*)xS + k * XSTR + q * 16) = pk;
    }
    __syncthreads();

    // ---- compute: rg owns rows rg*8..rg*8+7 (4 half2), ts = j / term slice (0..63) ----
    const char* xb = (const char*)xS + rg * 16;

    // quad (triangular): d = sum_{i<ts} buT[ts][i] * x_i ; weights from LDS ([g][ts]: 2-way, free)
    __half2 d[4] = {H2(0u), H2(0u), H2(0u), H2(0u)};
    {
        const int nii = (ts + 7) >> 3;             // 0..8; varies <=1 within a wave
        #pragma unroll
        for (int g = 0; g < 8; ++g) {
            if (g < nii) {
                uint4 w4 = *(const uint4*)(tbl + WS_BUTH + g * 1024 + ts * 16);
                const char* xkb = xb + g * 8 * XSTR;
                unsigned pw[4] = {w4.x, w4.y, w4.z, w4.w};
                #pragma unroll
                for (int p = 0; p < 4; ++p) {
                    __half2 blo = __half2half2(__ushort_as_half((unsigned short)(pw[p] & 0xFFFFu)));
                    __half2 bhi = __half2half2(__ushort_as_half((unsigned short)(pw[p] >> 16)));
                    uint4 x0 = *(const uint4*)(xkb + (2 * p + 0) * XSTR);
                    uint4 x1 = *(const uint4*)(xkb + (2 * p + 1) * XSTR);
                    qfma(blo, x0, d);
                    qfma(bhi, x1, d);
                }
            }
        }
    }
    __half2 acc[4];
    {
        __half2 a2 = __half2half2(__float2half(av));
        uint4 xj = *(const uint4*)(xb + ts * XSTR);
        acc[0] = __hmul2(__hadd2(a2, d[0]), H2(xj.x));
        acc[1] = __hmul2(__hadd2(a2, d[1]), H2(xj.y));
        acc[2] = __hmul2(__hadd2(a2, d[2]), H2(xj.z));
        acc[3] = __hmul2(__hadd2(a2, d[3]), H2(xj.w));
    }

    // ---- monomials: entries read from LDS ([m][ts]: conflict-free / 2-way) ----
    #pragma unroll
    for (int m = 0; m < 8; ++m) {
        uint2 p = *(const uint2*)(tbl + WS_P3 + m * 512 + ts * 8);
        uint4 v0 = *(const uint4*)(xb + (p.x & 0xFFFFu));
        uint4 v1 = *(const uint4*)(xb + (p.x >> 16));
        uint4 v2 = *(const uint4*)(xb + (p.y & 0xFFFFu));
        __half2 pr[4] = {H2(v0.x), H2(v0.y), H2(v0.z), H2(v0.w)};
        pmul(v1, pr);
        pmul(v2, pr);
        pacc(__half2half2(__ushort_as_half((unsigned short)(p.y >> 16))), pr, acc);
    }
    #pragma unroll
    for (int m = 0; m < 8; ++m) {
        uint4 p = *(const uint4*)(tbl + WS_P4 + m * 1024 + ts * 16);
        uint4 v0 = *(const uint4*)(xb + (p.x & 0xFFFFu));
        uint4 v1 = *(const uint4*)(xb + (p.x >> 16));
        uint4 v2 = *(const uint4*)(xb + (p.y & 0xFFFFu));
        uint4 v3 = *(const uint4*)(xb + (p.y >> 16));
        __half2 pr[4] = {H2(v0.x), H2(v0.y), H2(v0.z), H2(v0.w)};
        pmul(v1, pr);
        pmul(v2, pr);
        pmul(v3, pr);
        pacc(__half2half2(__ushort_as_half((unsigned short)(p.z & 0xFFFFu))), pr, acc);
    }
    #pragma unroll
    for (int m = 0; m < 8; ++m) {
        uint4 p = *(const uint4*)(tbl + WS_P5 + m * 1024 + ts * 16);
        uint4 v0 = *(const uint4*)(xb + (p.x & 0xFFFFu));
        uint4 v1 = *(const uint4*)(xb + (p.x >> 16));
        uint4 v2 = *(const uint4*)(xb + (p.y & 0xFFFFu));
        uint4 v3 = *(const uint4*)(xb + (p.y >> 16));
        uint4 v4 = *(const uint4*)(xb + (p.z & 0xFFFFu));
        __half2 pr[4] = {H2(v0.x), H2(v0.y), H2(v0.z), H2(v0.w)};
        pmul(v1, pr);
        pmul(v2, pr);
        pmul(v3, pr);
        pmul(v4, pr);
        pacc(__half2half2(__ushort_as_half((unsigned short)(p.z >> 16))), pr, acc);
    }

    // ---- reduce 16 ts-partials per wave in fp32, then cross-wave via LDS ----
    float f[8];
    #pragma unroll
    for (int e = 0; e < 4; ++e) {
        f[2 * e]     = __low2float(acc[e]);
        f[2 * e + 1] = __high2float(acc[e]);
    }
    #pragma unroll
    for (int mask = 4; mask <= 32; mask <<= 1) {
        #pragma unroll
        for (int r = 0; r < 8; ++r) f[r] += __shfl_xor(f[r], mask, 64);
    }
    const int w = tid >> 6, lane = tid & 63;
    if (lane < 4) {
        #pragma unroll
        for (int r = 0; r < 8; ++r) red[w][lane][r] = f[r];
    }
    __syncthreads();
    if (tid < 32) {
        int g = tid >> 3, e = tid & 7;
        out[row0 + tid] = red[0][g][e] + red[1][g][e] + red[2][g][e] + red[3][g][e];
    }
}

extern "C" void kernel_launch(void* const* d_in, const int* in_sizes, int n_in,
                              void* d_out, int out_size, void* d_ws, size_t ws_size,
                              hipStream_t stream) {
    const float* x  = (const float*)d_in[0];
    const int*   S  = (const int*)d_in[1];
    const float* a  = (const float*)d_in[2];
    const float* b  = (const float*)d_in[3];
    const int*   i3 = (const int*)d_in[4];
    const float* c3 = (const float*)d_in[5];
    const int*   i4 = (const int*)d_in[6];
    const float* c4 = (const float*)d_in[7];
    const int*   i5 = (const int*)d_in[8];
    const float* c5 = (const float*)d_in[9];
    unsigned char* ws = (unsigned char*)d_ws;
    float* out = (float*)d_out;

    prepack<<<16, NT, 0, stream>>>(b, i3, c3, i4, c4, i5, c5, ws);
    poly_main<<<32768 / RPB, NT, 0, stream>>>(x, S, a, ws, out);
}